// Round 3
// baseline (248.061 us; speedup 1.0000x reference)
//
#include <hip/hip_runtime.h>
#include <stdint.h>

#define NFFT    1024
#define HOP     160
#define NMELS   160
#define SEG     32000
#define PADW    512
#define XLEN    33024            // SEG + 2*PADW
#define NFRAMES 201
#define NBATCH  256
#define NFREQ   256              // bins 0..255 cover all nonzero mel weights
#define TOTFR   (NBATCH * NFRAMES)   // 51456 = 402 * 128
#define FBW     12
#define BM      128
#define BK      64
#define NSTEP   (NFFT / BK)      // 16

using bf16x8 = __attribute__((ext_vector_type(8))) __bf16;
using f32x4  = __attribute__((ext_vector_type(4))) float;

static __device__ __forceinline__ uint16_t f2bf(float f) {
    union { float f; uint32_t u; } v; v.f = f;
    return (uint16_t)((v.u + 0x7FFFu + ((v.u >> 16) & 1u)) >> 16);
}
static __device__ __forceinline__ float bf2f(uint16_t h) {
    union { uint32_t u; float f; } v; v.u = (uint32_t)h << 16;
    return v.f;
}

static __device__ __forceinline__ void gload16(const void* g, void* l) {
    __builtin_amdgcn_global_load_lds(
        (const __attribute__((address_space(1))) uint32_t*)(uintptr_t)g,
        (__attribute__((address_space(3))) uint32_t*)(uintptr_t)l,
        16, 0, 0);
}

// ---- prep 1: reflect-pad waveform, convert to bf16
__global__ void k_pad(const float* __restrict__ wav, uint16_t* __restrict__ wp) {
    int i = blockIdx.x * 256 + threadIdx.x;
    int b = blockIdx.y;
    if (i >= XLEN) return;
    int j = i - PADW;
    j = (j < 0) ? -j : ((j >= SEG) ? (2 * SEG - 2 - j) : j);
    wp[b * XLEN + i] = f2bf(wav[b * SEG + j]);
}

// ---- prep 2: BT[mat][n][k] = bf16(dft[mat][n][k] * window[k]), n<256, k<1024
__global__ void k_bt(const float* __restrict__ dre, const float* __restrict__ dimg,
                     const float* __restrict__ win, uint16_t* __restrict__ BT) {
    int idx = blockIdx.x * 256 + threadIdx.x;
    int mat = idx >> 18;
    int n   = (idx >> 10) & 255;
    int k   = idx & 1023;
    const float* src = mat ? dimg : dre;
    BT[idx] = f2bf(src[n * 1024 + k] * win[k]);
}

// ---- prep 3: compact sparse mel filterbank rows
__global__ void k_fb(const float* __restrict__ fb, int* __restrict__ klo,
                     int* __restrict__ kw, float* __restrict__ fbv) {
    int m = threadIdx.x;
    if (m >= NMELS) return;
    int lo = -1, hi = -1;
    for (int f = 0; f < NFREQ; ++f) {
        float v = fb[m * 513 + f];
        if (v > 0.f) { if (lo < 0) lo = f; hi = f; }
    }
    int w = (lo < 0) ? 0 : (hi - lo + 1);
    if (w > FBW) w = FBW;
    if (lo < 0) lo = 0;
    klo[m] = lo; kw[m] = w;
    for (int j = 0; j < w; ++j) fbv[m * FBW + j] = fb[m * 513 + lo + j];
}

// ---- main GEMM: 128 frames x 256 bins per block, K=1024, double-buffered LDS
// LDS: [0,16K) A0 | [16K,32K) A1 | [32K,96K) B0 | [96K,160K) B1
// Rows of 128B (8 chunks of 16B), chunk-swizzled: chunk ^= row&7 (both sides).
// Schedule: 2 phases per K-tile {stage-half issue, ds_read kh, setprio MFMA},
// counted vmcnt(5) once per tile (never drained mid-loop), mid-tile barrier.
__global__ __launch_bounds__(512, 2) void k_main(
    const uint16_t* __restrict__ wp, const uint16_t* __restrict__ BT,
    const int* __restrict__ klo, const int* __restrict__ kw,
    const float* __restrict__ fbv, float* __restrict__ out)
{
    __shared__ uint4 smem4[163840 / 16];     // 160 KB
    char* smem = (char*)smem4;

    const int tid  = threadIdx.x;
    const int lane = tid & 63;
    const int wave = tid >> 6;               // 8 waves: 2(M) x 4(N)
    const int wm = wave >> 2, wn = wave & 3;
    const int l15 = lane & 15, lg = lane >> 4;
    const int gBase = blockIdx.x * BM;

    // ---- staging slots: 80 slots of 1KB (8 rows x 128B), 10 per wave
    const int lrow8 = lane >> 3;
    const int lchk  = lane & 7;
    const int schunk = lchk ^ lrow8;         // inverse-swizzled source chunk
    const uint16_t* srcp[10];
    uint32_t dstoff[10], dststep[10];
    #pragma unroll
    for (int i = 0; i < 10; ++i) {
        int s = wave * 10 + i;
        if (s < 16) {                        // A slots: frames
            int row = s * 8 + lrow8;
            int g = gBase + row;
            int b = g / NFRAMES, t = g - b * NFRAMES;
            srcp[i]   = wp + (size_t)b * XLEN + t * HOP + schunk * 8;
            dstoff[i] = (uint32_t)s * 1024;
            dststep[i] = 16384;
        } else {                             // B slots: DFT rows (R then I)
            int r = (s - 16) * 8 + lrow8;
            srcp[i]   = BT + (size_t)r * 1024 + schunk * 8;
            dstoff[i] = 32768u + (uint32_t)(s - 16) * 1024;
            dststep[i] = 65536;
        }
    }

    auto STAGE_HALF = [&](int buf, int ks, int h) {
        #pragma unroll
        for (int i = h * 5; i < h * 5 + 5; ++i)
            gload16(srcp[i] + (size_t)ks * BK,
                    smem + dstoff[i] + (buf ? dststep[i] : 0u));
    };

    f32x4 accR[4][4], accI[4][4];
    #pragma unroll
    for (int mi = 0; mi < 4; ++mi)
        #pragma unroll
        for (int ni = 0; ni < 4; ++ni) {
            accR[mi][ni] = f32x4{0.f, 0.f, 0.f, 0.f};
            accI[mi][ni] = f32x4{0.f, 0.f, 0.f, 0.f};
        }

    STAGE_HALF(0, 0, 0);
    STAGE_HALF(0, 0, 1);

    #pragma unroll 2
    for (int t = 0; t < NSTEP; ++t) {
        const int cur = t & 1;
        const char* Ac = smem + cur * 16384;
        const char* Bc = smem + 32768 + cur * 65536;

        // ======== phase A (kh = 0) ========
        if (t < NSTEP - 1) {
            STAGE_HALF(cur ^ 1, t + 1, 0);               // 5 loads in flight
            asm volatile("s_waitcnt vmcnt(5)" ::: "memory");  // tile t landed
        } else {
            asm volatile("s_waitcnt vmcnt(0)" ::: "memory");
        }
        __builtin_amdgcn_s_barrier();
        __builtin_amdgcn_sched_barrier(0);
        {
            const int swz = (lg ^ (l15 & 7)) * 16;
            bf16x8 a[4], br[4], bi[4];
            #pragma unroll
            for (int mi = 0; mi < 4; ++mi)
                a[mi] = *(const bf16x8*)(Ac + (wm * 64 + mi * 16 + l15) * 128 + swz);
            #pragma unroll
            for (int ni = 0; ni < 4; ++ni) {
                br[ni] = *(const bf16x8*)(Bc + (wn * 64 + ni * 16 + l15) * 128 + swz);
                bi[ni] = *(const bf16x8*)(Bc + 32768 + (wn * 64 + ni * 16 + l15) * 128 + swz);
            }
            __builtin_amdgcn_s_setprio(1);
            #pragma unroll
            for (int mi = 0; mi < 4; ++mi)
                #pragma unroll
                for (int ni = 0; ni < 4; ++ni) {
                    accR[mi][ni] = __builtin_amdgcn_mfma_f32_16x16x32_bf16(
                        a[mi], br[ni], accR[mi][ni], 0, 0, 0);
                    accI[mi][ni] = __builtin_amdgcn_mfma_f32_16x16x32_bf16(
                        a[mi], bi[ni], accI[mi][ni], 0, 0, 0);
                }
            __builtin_amdgcn_s_setprio(0);
        }
        __builtin_amdgcn_sched_barrier(0);
        __builtin_amdgcn_s_barrier();

        // ======== phase B (kh = 1) ========
        if (t < NSTEP - 1) STAGE_HALF(cur ^ 1, t + 1, 1);
        {
            const int swz = ((lg + 4) ^ (l15 & 7)) * 16;
            bf16x8 a[4], br[4], bi[4];
            #pragma unroll
            for (int mi = 0; mi < 4; ++mi)
                a[mi] = *(const bf16x8*)(Ac + (wm * 64 + mi * 16 + l15) * 128 + swz);
            #pragma unroll
            for (int ni = 0; ni < 4; ++ni) {
                br[ni] = *(const bf16x8*)(Bc + (wn * 64 + ni * 16 + l15) * 128 + swz);
                bi[ni] = *(const bf16x8*)(Bc + 32768 + (wn * 64 + ni * 16 + l15) * 128 + swz);
            }
            __builtin_amdgcn_s_setprio(1);
            #pragma unroll
            for (int mi = 0; mi < 4; ++mi)
                #pragma unroll
                for (int ni = 0; ni < 4; ++ni) {
                    accR[mi][ni] = __builtin_amdgcn_mfma_f32_16x16x32_bf16(
                        a[mi], br[ni], accR[mi][ni], 0, 0, 0);
                    accI[mi][ni] = __builtin_amdgcn_mfma_f32_16x16x32_bf16(
                        a[mi], bi[ni], accI[mi][ni], 0, 0, 0);
                }
            __builtin_amdgcn_s_setprio(0);
        }
        __builtin_amdgcn_sched_barrier(0);
        __builtin_amdgcn_s_barrier();
    }

    // ---- epilogue: power (bf16) into B0 region [128][256], col-swizzled
    uint16_t* pw16 = (uint16_t*)(smem + 32768);
    #pragma unroll
    for (int mi = 0; mi < 4; ++mi)
        #pragma unroll
        for (int ni = 0; ni < 4; ++ni)
            #pragma unroll
            for (int e = 0; e < 4; ++e) {
                int row = wm * 64 + mi * 16 + lg * 4 + e;
                int col = wn * 64 + ni * 16 + l15;
                float r = accR[mi][ni][e], im = accI[mi][ni][e];
                pw16[row * 256 + (col ^ ((row & 31) << 1))] = f2bf(r * r + im * im);
            }
    __syncthreads();

    // ---- sparse mel projection + transposed store out[b][m][t]
    for (int idx = tid; idx < NMELS * BM; idx += 512) {
        int m  = idx >> 7;
        int ti = idx & 127;
        int g = gBase + ti;
        int b = g / NFRAMES, t = g - b * NFRAMES;
        int lo = klo[m], w = kw[m];
        int sw = (ti & 31) << 1;
        const uint16_t* prow = pw16 + ti * 256;
        float acc = 0.f;
        for (int j = 0; j < w; ++j)
            acc += fbv[m * FBW + j] * bf2f(prow[(lo + j) ^ sw]);
        out[(size_t)b * (NMELS * NFRAMES) + m * NFRAMES + t] = acc;
    }
}

extern "C" void kernel_launch(void* const* d_in, const int* in_sizes, int n_in,
                              void* d_out, int out_size, void* d_ws, size_t ws_size,
                              hipStream_t stream) {
    const float* wav  = (const float*)d_in[0];
    const float* win  = (const float*)d_in[1];
    const float* dre  = (const float*)d_in[2];
    const float* dimg = (const float*)d_in[3];
    const float* mfb  = (const float*)d_in[4];
    float* out = (float*)d_out;

    uint8_t* ws = (uint8_t*)d_ws;
    uint16_t* BT  = (uint16_t*)ws;                       // 1 MB
    uint16_t* wp  = (uint16_t*)(ws + (1u << 20));        // 16.9 MB
    size_t off = (1u << 20) + (size_t)NBATCH * XLEN * 2;
    int*   klo = (int*)(ws + off);
    int*   kw  = (int*)(ws + off + 640);
    float* fbv = (float*)(ws + off + 1280);

    hipLaunchKernelGGL(k_bt,  dim3(2048),     dim3(256), 0, stream, dre, dimg, win, BT);
    hipLaunchKernelGGL(k_pad, dim3(129, 256), dim3(256), 0, stream, wav, wp);
    hipLaunchKernelGGL(k_fb,  dim3(1),        dim3(192), 0, stream, mfb, klo, kw, fbv);
    hipLaunchKernelGGL(k_main, dim3(TOTFR / BM), dim3(512), 0, stream,
                       wp, BT, klo, kw, fbv, out);
}

// Round 4
// 142.256 us; speedup vs baseline: 1.7438x; 1.7438x over previous
//
#include <hip/hip_runtime.h>
#include <stdint.h>

#define NFFT    1024
#define HOP     160
#define NMELS   160
#define SEG     32000
#define PADW    512
#define XLEN    33024            // SEG + 2*PADW
#define NFRAMES 201
#define NBATCH  256
#define NFREQ   256              // bins 0..255 cover all nonzero mel weights
#define TOTFR   (NBATCH * NFRAMES)   // 51456 = 402 * 128
#define FBW     12
#define BM      128
#define BN      128              // real bins per block (2 block-columns)
#define BK      32
#define NSTEP   (NFFT / BK)      // 32

using bf16x8 = __attribute__((ext_vector_type(8))) __bf16;
using f32x4  = __attribute__((ext_vector_type(4))) float;

static __device__ __forceinline__ uint16_t f2bf(float f) {
    union { float f; uint32_t u; } v; v.f = f;
    return (uint16_t)((v.u + 0x7FFFu + ((v.u >> 16) & 1u)) >> 16);
}
static __device__ __forceinline__ float bf2f(uint16_t h) {
    union { uint32_t u; float f; } v; v.u = (uint32_t)h << 16;
    return v.f;
}

static __device__ __forceinline__ void gload16(const void* g, void* l) {
    __builtin_amdgcn_global_load_lds(
        (const __attribute__((address_space(1))) uint32_t*)(uintptr_t)g,
        (__attribute__((address_space(3))) uint32_t*)(uintptr_t)l,
        16, 0, 0);
}

// ---- prep 1: reflect-pad waveform, convert to bf16
__global__ void k_pad(const float* __restrict__ wav, uint16_t* __restrict__ wp) {
    int i = blockIdx.x * 256 + threadIdx.x;
    int b = blockIdx.y;
    if (i >= XLEN) return;
    int j = i - PADW;
    j = (j < 0) ? -j : ((j >= SEG) ? (2 * SEG - 2 - j) : j);
    wp[b * XLEN + i] = f2bf(wav[b * SEG + j]);
}

// ---- prep 2: BT[mat][n][k] = bf16(dft[mat][n][k] * window[k]), n<256, k<1024
__global__ void k_bt(const float* __restrict__ dre, const float* __restrict__ dimg,
                     const float* __restrict__ win, uint16_t* __restrict__ BT) {
    int idx = blockIdx.x * 256 + threadIdx.x;
    int mat = idx >> 18;
    int n   = (idx >> 10) & 255;
    int k   = idx & 1023;
    const float* src = mat ? dimg : dre;
    BT[idx] = f2bf(src[n * 1024 + k] * win[k]);
}

// ---- prep 3: compact sparse mel filterbank rows
__global__ void k_fb(const float* __restrict__ fb, int* __restrict__ klo,
                     int* __restrict__ kw, float* __restrict__ fbv) {
    int m = threadIdx.x;
    if (m >= NMELS) return;
    int lo = -1, hi = -1;
    for (int f = 0; f < NFREQ; ++f) {
        float v = fb[m * 513 + f];
        if (v > 0.f) { if (lo < 0) lo = f; hi = f; }
    }
    int w = (lo < 0) ? 0 : (hi - lo + 1);
    if (w > FBW) w = FBW;
    if (lo < 0) lo = 0;
    klo[m] = lo; kw[m] = w;
    for (int j = 0; j < w; ++j) fbv[m * FBW + j] = fb[m * 513 + lo + j];
}

// ---- prep 4: zero the outputs that will be atomically accumulated
// (mel rows straddling the bin-128 block boundary, or empty rows)
__global__ void k_zero(const int* __restrict__ klo, const int* __restrict__ kw,
                       float* __restrict__ out) {
    int b = blockIdx.x;
    for (int m = 0; m < NMELS; ++m) {
        int lo = klo[m], w = kw[m];
        bool straddle = (lo < BN && lo + w > BN);
        if (!(straddle || w == 0)) continue;
        for (int t = threadIdx.x; t < NFRAMES; t += blockDim.x)
            out[(size_t)b * NMELS * NFRAMES + m * NFRAMES + t] = 0.f;
    }
}

// ---- main GEMM: 128 frames x 128 bins (R+I) per block, K=1024
// Triple-buffered LDS (72KB -> 2 blocks/CU):
//   A[3][128][32] bf16 @ 0,8K,16K ; B[3][256][32] bf16 @ 24K,40K,56K
//   (B virtual rows: 0..127 = Re bins, 128..255 = Im bins)
// 64B rows: ds_read_b128 with row=l15,chunk=lg is bank-conflict-free, no swizzle.
// Counted vmcnt(6): 2 K-tiles of loads always in flight (T4).
__global__ __launch_bounds__(512, 4) void k_main(
    const uint16_t* __restrict__ wp, const uint16_t* __restrict__ BT,
    const int* __restrict__ klo, const int* __restrict__ kw,
    const float* __restrict__ fbv, float* __restrict__ out)
{
    __shared__ uint4 smem4[73728 / 16];          // 72 KB
    char* smem = (char*)smem4;

    const int tid  = threadIdx.x;
    const int lane = tid & 63;
    const int wave = tid >> 6;                   // 8 waves: 2(M) x 4(N)
    const int wm = wave >> 2, wn = wave & 3;
    const int l15 = lane & 15, lg = lane >> 4;
    const int gBase = blockIdx.x * BM;
    const int nb    = blockIdx.y;                // bin half: 0 or 1

    // ---- staging: 24 slots of 1KB (16 rows x 64B), 3 per wave
    const int lrow = lane >> 2;                  // row within slot
    const int lchk = lane & 3;                   // 16B chunk within row
    const uint16_t* srcp[3];
    uint32_t rel[3];
    bool isA[3];
    #pragma unroll
    for (int i = 0; i < 3; ++i) {
        int s = wave * 3 + i;
        if (s < 8) {                             // A: frames
            int row = s * 16 + lrow;
            int g = gBase + row;
            int b = g / NFRAMES, t = g - b * NFRAMES;
            srcp[i] = wp + (size_t)b * XLEN + t * HOP + lchk * 8;
            rel[i]  = (uint32_t)s * 1024 + lane * 16;
            isA[i]  = true;
        } else {                                 // B: virtual rows (Re,Im)
            int vr  = (s - 8) * 16 + lrow;       // 0..255
            int mat = vr >> 7, bin = vr & 127;
            srcp[i] = BT + (size_t)(mat * 256 + nb * BN + bin) * 1024 + lchk * 8;
            rel[i]  = (uint32_t)(s - 8) * 1024 + lane * 16;
            isA[i]  = false;
        }
    }

    auto STAGE = [&](uint32_t aoff, uint32_t boff, int ks) {
        #pragma unroll
        for (int i = 0; i < 3; ++i)
            gload16(srcp[i] + (size_t)ks * BK,
                    smem + (isA[i] ? aoff : boff) + rel[i]);
    };

    f32x4 accR[4][2], accI[4][2];
    #pragma unroll
    for (int mi = 0; mi < 4; ++mi)
        #pragma unroll
        for (int ni = 0; ni < 2; ++ni) {
            accR[mi][ni] = f32x4{0.f, 0.f, 0.f, 0.f};
            accI[mi][ni] = f32x4{0.f, 0.f, 0.f, 0.f};
        }

    uint32_t a0 = 0,     a1 = 8192,  a2 = 16384;
    uint32_t b0 = 24576, b1 = 40960, b2 = 57344;
    STAGE(a0, b0, 0);
    STAGE(a1, b1, 1);

    for (int t = 0; t < NSTEP; ++t) {
        if (t + 2 < NSTEP) {
            STAGE(a2, b2, t + 2);
            __builtin_amdgcn_sched_barrier(0);
            asm volatile("s_waitcnt vmcnt(6)" ::: "memory");
        } else if (t + 1 < NSTEP) {
            __builtin_amdgcn_sched_barrier(0);
            asm volatile("s_waitcnt vmcnt(3)" ::: "memory");
        } else {
            __builtin_amdgcn_sched_barrier(0);
            asm volatile("s_waitcnt vmcnt(0)" ::: "memory");
        }
        __builtin_amdgcn_s_barrier();
        __builtin_amdgcn_sched_barrier(0);

        const char* Ac = smem + a0;
        const char* Bc = smem + b0;
        bf16x8 a[4], br[2], bi[2];
        #pragma unroll
        for (int mi = 0; mi < 4; ++mi)
            a[mi] = *(const bf16x8*)(Ac + (wm * 64 + mi * 16 + l15) * 64 + lg * 16);
        #pragma unroll
        for (int ni = 0; ni < 2; ++ni) {
            br[ni] = *(const bf16x8*)(Bc + (wn * 32 + ni * 16 + l15) * 64 + lg * 16);
            bi[ni] = *(const bf16x8*)(Bc + 8192 + (wn * 32 + ni * 16 + l15) * 64 + lg * 16);
        }
        __builtin_amdgcn_s_setprio(1);
        #pragma unroll
        for (int mi = 0; mi < 4; ++mi)
            #pragma unroll
            for (int ni = 0; ni < 2; ++ni) {
                accR[mi][ni] = __builtin_amdgcn_mfma_f32_16x16x32_bf16(
                    a[mi], br[ni], accR[mi][ni], 0, 0, 0);
                accI[mi][ni] = __builtin_amdgcn_mfma_f32_16x16x32_bf16(
                    a[mi], bi[ni], accI[mi][ni], 0, 0, 0);
            }
        __builtin_amdgcn_s_setprio(0);
        __builtin_amdgcn_sched_barrier(0);
        __builtin_amdgcn_s_barrier();

        uint32_t ta = a0; a0 = a1; a1 = a2; a2 = ta;
        uint32_t tb = b0; b0 = b1; b1 = b2; b2 = tb;
    }

    // ---- epilogue: power (bf16) [128][128] at smem+24576, col-swizzled
    uint16_t* pw16 = (uint16_t*)(smem + 24576);
    #pragma unroll
    for (int mi = 0; mi < 4; ++mi)
        #pragma unroll
        for (int ni = 0; ni < 2; ++ni)
            #pragma unroll
            for (int e = 0; e < 4; ++e) {
                int row = wm * 64 + mi * 16 + lg * 4 + e;
                int col = wn * 32 + ni * 16 + l15;
                float r = accR[mi][ni][e], im = accI[mi][ni][e];
                pw16[row * BN + (col ^ ((row & 31) << 1))] = f2bf(r * r + im * im);
            }
    __syncthreads();

    // ---- sparse mel projection + transposed store/atomic out[b][m][t]
    const int nbase = nb * BN;
    for (int idx = tid; idx < NMELS * BM; idx += 512) {
        int m  = idx >> 7;
        int ti = idx & 127;
        int lo = klo[m], w = kw[m];
        int i0 = lo < nbase ? nbase : lo;
        int i1 = (lo + w < nbase + BN) ? (lo + w) : (nbase + BN);
        if (i1 <= i0) continue;
        int g = gBase + ti;
        int b = g / NFRAMES, t = g - b * NFRAMES;
        int sw = (ti & 31) << 1;
        const uint16_t* prow = pw16 + ti * BN;
        float acc = 0.f;
        for (int j = i0; j < i1; ++j)
            acc += fbv[m * FBW + (j - lo)] * bf2f(prow[(j - nbase) ^ sw]);
        float* dst = out + (size_t)b * (NMELS * NFRAMES) + m * NFRAMES + t;
        bool full = (lo >= nbase) && (lo + w <= nbase + BN);
        if (full) *dst = acc;
        else      atomicAdd(dst, acc);
    }
}

extern "C" void kernel_launch(void* const* d_in, const int* in_sizes, int n_in,
                              void* d_out, int out_size, void* d_ws, size_t ws_size,
                              hipStream_t stream) {
    const float* wav  = (const float*)d_in[0];
    const float* win  = (const float*)d_in[1];
    const float* dre  = (const float*)d_in[2];
    const float* dimg = (const float*)d_in[3];
    const float* mfb  = (const float*)d_in[4];
    float* out = (float*)d_out;

    uint8_t* ws = (uint8_t*)d_ws;
    uint16_t* BT  = (uint16_t*)ws;                       // 1 MB
    uint16_t* wp  = (uint16_t*)(ws + (1u << 20));        // 16.9 MB
    size_t off = (1u << 20) + (size_t)NBATCH * XLEN * 2;
    int*   klo = (int*)(ws + off);
    int*   kw  = (int*)(ws + off + 640);
    float* fbv = (float*)(ws + off + 1280);

    hipLaunchKernelGGL(k_bt,   dim3(2048),     dim3(256), 0, stream, dre, dimg, win, BT);
    hipLaunchKernelGGL(k_pad,  dim3(129, 256), dim3(256), 0, stream, wav, wp);
    hipLaunchKernelGGL(k_fb,   dim3(1),        dim3(192), 0, stream, mfb, klo, kw, fbv);
    hipLaunchKernelGGL(k_zero, dim3(256),      dim3(256), 0, stream, klo, kw, out);
    hipLaunchKernelGGL(k_main, dim3(TOTFR / BM, 2), dim3(512), 0, stream,
                       wp, BT, klo, kw, fbv, out);
}

// Round 5
// 140.444 us; speedup vs baseline: 1.7663x; 1.0129x over previous
//
#include <hip/hip_runtime.h>
#include <stdint.h>

#define NFFT    1024
#define HOP     160
#define NMELS   160
#define SEG     32000
#define PADW    512
#define XLEN    33024            // SEG + 2*PADW
#define NFRAMES 201
#define NBATCH  256
#define NFREQ   256              // bins 0..255 cover all nonzero mel weights
#define TOTFR   (NBATCH * NFRAMES)   // 51456 = 402 * 128
#define FBW     12
#define BM      128
#define BN      128              // real bins per block (2 block-columns)
#define BK      32
#define NSTEP   (NFFT / BK)      // 32

using bf16x8 = __attribute__((ext_vector_type(8))) __bf16;
using f32x4  = __attribute__((ext_vector_type(4))) float;

static __device__ __forceinline__ uint16_t f2bf(float f) {
    union { float f; uint32_t u; } v; v.f = f;
    return (uint16_t)((v.u + 0x7FFFu + ((v.u >> 16) & 1u)) >> 16);
}
static __device__ __forceinline__ float bf2f(uint16_t h) {
    union { uint32_t u; float f; } v; v.u = (uint32_t)h << 16;
    return v.f;
}

static __device__ __forceinline__ void gload16(const void* g, void* l) {
    __builtin_amdgcn_global_load_lds(
        (const __attribute__((address_space(1))) uint32_t*)(uintptr_t)g,
        (__attribute__((address_space(3))) uint32_t*)(uintptr_t)l,
        16, 0, 0);
}

// ---- prep 1: reflect-pad waveform -> bf16, 8 elems/thread, vectorized interior
__global__ void k_pad(const float* __restrict__ wav, uint16_t* __restrict__ wp) {
    int i0 = (blockIdx.x * 256 + threadIdx.x) * 8;
    int b  = blockIdx.y;
    if (i0 >= XLEN) return;
    uint16_t r[8];
    if (i0 >= PADW && i0 + 8 <= PADW + SEG) {        // interior: aligned float4 x2
        const float* s = wav + (size_t)b * SEG + (i0 - PADW);
        float4 v0 = *(const float4*)s;
        float4 v1 = *(const float4*)(s + 4);
        r[0]=f2bf(v0.x); r[1]=f2bf(v0.y); r[2]=f2bf(v0.z); r[3]=f2bf(v0.w);
        r[4]=f2bf(v1.x); r[5]=f2bf(v1.y); r[6]=f2bf(v1.z); r[7]=f2bf(v1.w);
    } else {                                          // reflect edges, scalar
        #pragma unroll
        for (int e = 0; e < 8; ++e) {
            int i = i0 + e;
            int j = i - PADW;
            j = (j < 0) ? -j : ((j >= SEG) ? (2 * SEG - 2 - j) : j);
            r[e] = f2bf(wav[(size_t)b * SEG + j]);
        }
    }
    *(uint4*)(wp + (size_t)b * XLEN + i0) = *(const uint4*)r;
}

// ---- prep 2: BT[mat][n][k] = bf16(dft[mat][n][k] * window[k]), 8 elems/thread
__global__ void k_bt(const float* __restrict__ dre, const float* __restrict__ dimg,
                     const float* __restrict__ win, uint16_t* __restrict__ BT) {
    int idx8 = blockIdx.x * 256 + threadIdx.x;       // 65536 threads
    int mat = idx8 >> 15;
    int n   = (idx8 >> 7) & 255;
    int k0  = (idx8 & 127) * 8;
    const float* src = (mat ? dimg : dre) + (size_t)n * 1024 + k0;
    const float* w   = win + k0;
    float4 s0 = *(const float4*)src,       s1 = *(const float4*)(src + 4);
    float4 w0 = *(const float4*)w,         w1 = *(const float4*)(w + 4);
    uint16_t r[8];
    r[0]=f2bf(s0.x*w0.x); r[1]=f2bf(s0.y*w0.y); r[2]=f2bf(s0.z*w0.z); r[3]=f2bf(s0.w*w0.w);
    r[4]=f2bf(s1.x*w1.x); r[5]=f2bf(s1.y*w1.y); r[6]=f2bf(s1.z*w1.z); r[7]=f2bf(s1.w*w1.w);
    *(uint4*)(BT + (size_t)idx8 * 8) = *(const uint4*)r;
}

// ---- prep 3: compact sparse mel filterbank rows
__global__ void k_fb(const float* __restrict__ fb, int* __restrict__ klo,
                     int* __restrict__ kw, float* __restrict__ fbv) {
    int m = threadIdx.x;
    if (m >= NMELS) return;
    int lo = -1, hi = -1;
    for (int f = 0; f < NFREQ; ++f) {
        float v = fb[m * 513 + f];
        if (v > 0.f) { if (lo < 0) lo = f; hi = f; }
    }
    int w = (lo < 0) ? 0 : (hi - lo + 1);
    if (w > FBW) w = FBW;
    if (lo < 0) lo = 0;
    klo[m] = lo; kw[m] = w;
    for (int j = 0; j < w; ++j) fbv[m * FBW + j] = fb[m * 513 + lo + j];
}

// ---- prep 4: zero outputs that get atomicAdd'ed (straddle/empty mel rows)
__global__ void k_zero(const int* __restrict__ klo, const int* __restrict__ kw,
                       float* __restrict__ out) {
    int b = blockIdx.x;
    for (int m = 0; m < NMELS; ++m) {
        int lo = klo[m], w = kw[m];
        bool straddle = (lo < BN && lo + w > BN);
        if (!(straddle || w == 0)) continue;
        for (int t = threadIdx.x; t < NFRAMES; t += blockDim.x)
            out[(size_t)b * NMELS * NFRAMES + m * NFRAMES + t] = 0.f;
    }
}

// ---- main GEMM: 128 frames x 128 bins (R+I) per block, K=1024
// Triple-buffered LDS (72KB -> 2 blocks/CU):
//   A[3][128][32] @ 0,8K,16K ; B[3][256][32] @ 24K,40K,56K (vrows: Re 0-127, Im 128-255)
// 64B rows, chunk swizzle c ^= (row>>1)&3 (pre-swizzled source + swizzled read):
//   8-lane groups hit start banks {0,16,4,20,8,24,12,28} -> full 32-bank coverage.
// One barrier per K-step; counted vmcnt(3) keeps 2 tiles of loads in flight.
__global__ __launch_bounds__(512, 4) void k_main(
    const uint16_t* __restrict__ wp, const uint16_t* __restrict__ BT,
    const int* __restrict__ klo, const int* __restrict__ kw,
    const float* __restrict__ fbv, float* __restrict__ out)
{
    __shared__ uint4 smem4[73728 / 16];          // 72 KB
    char* smem = (char*)smem4;

    const int tid  = threadIdx.x;
    const int lane = tid & 63;
    const int wave = tid >> 6;                   // 8 waves: 2(M) x 4(N)
    const int wm = wave >> 2, wn = wave & 3;
    const int l15 = lane & 15, lg = lane >> 4;
    const int gBase = blockIdx.x * BM;
    const int nb    = blockIdx.y;                // bin half: 0 or 1

    // ---- staging: 24 slots of 1KB (16 rows x 64B), 3 per wave
    const int lrow = lane >> 2;                  // row within slot
    const int lchk = lane & 3;                   // linear 16B chunk pos in LDS
    const int schunk = lchk ^ ((lrow >> 1) & 3); // inverse-swizzled source chunk
    const uint16_t* srcp[3];
    uint32_t rel[3];
    bool isA[3];
    #pragma unroll
    for (int i = 0; i < 3; ++i) {
        int s = wave * 3 + i;
        if (s < 8) {                             // A: frames
            int row = s * 16 + lrow;
            int g = gBase + row;
            int b = g / NFRAMES, t = g - b * NFRAMES;
            srcp[i] = wp + (size_t)b * XLEN + t * HOP + schunk * 8;
            rel[i]  = (uint32_t)s * 1024 + lane * 16;
            isA[i]  = true;
        } else {                                 // B: virtual rows (Re,Im)
            int vr  = (s - 8) * 16 + lrow;       // 0..255
            int mat = vr >> 7, bin = vr & 127;
            srcp[i] = BT + (size_t)(mat * 256 + nb * BN + bin) * 1024 + schunk * 8;
            rel[i]  = (uint32_t)(s - 8) * 1024 + lane * 16;
            isA[i]  = false;
        }
    }

    auto STAGE = [&](uint32_t aoff, uint32_t boff, int ks) {
        #pragma unroll
        for (int i = 0; i < 3; ++i)
            gload16(srcp[i] + (size_t)ks * BK,
                    smem + (isA[i] ? aoff : boff) + rel[i]);
    };

    f32x4 accR[4][2], accI[4][2];
    #pragma unroll
    for (int mi = 0; mi < 4; ++mi)
        #pragma unroll
        for (int ni = 0; ni < 2; ++ni) {
            accR[mi][ni] = f32x4{0.f, 0.f, 0.f, 0.f};
            accI[mi][ni] = f32x4{0.f, 0.f, 0.f, 0.f};
        }

    uint32_t a0 = 0,     a1 = 8192,  a2 = 16384;
    uint32_t b0 = 24576, b1 = 40960, b2 = 57344;
    STAGE(a0, b0, 0);
    STAGE(a1, b1, 1);
    asm volatile("s_waitcnt vmcnt(3)" ::: "memory");
    __builtin_amdgcn_s_barrier();
    __builtin_amdgcn_sched_barrier(0);

    // read-side swizzled chunk offset (bytes within 64B row)
    const int rchunk = (lg ^ ((l15 >> 1) & 3)) * 16;

    for (int t = 0; t < NSTEP; ++t) {
        const char* Ac = smem + a0;
        const char* Bc = smem + b0;
        bf16x8 a[4], br[2], bi[2];
        #pragma unroll
        for (int mi = 0; mi < 4; ++mi)
            a[mi] = *(const bf16x8*)(Ac + (wm * 64 + mi * 16 + l15) * 64 + rchunk);
        #pragma unroll
        for (int ni = 0; ni < 2; ++ni) {
            br[ni] = *(const bf16x8*)(Bc + (wn * 32 + ni * 16 + l15) * 64 + rchunk);
            bi[ni] = *(const bf16x8*)(Bc + 8192 + (wn * 32 + ni * 16 + l15) * 64 + rchunk);
        }
        if (t + 2 < NSTEP) STAGE(a2, b2, t + 2);

        __builtin_amdgcn_s_setprio(1);
        #pragma unroll
        for (int mi = 0; mi < 4; ++mi)
            #pragma unroll
            for (int ni = 0; ni < 2; ++ni) {
                accR[mi][ni] = __builtin_amdgcn_mfma_f32_16x16x32_bf16(
                    a[mi], br[ni], accR[mi][ni], 0, 0, 0);
                accI[mi][ni] = __builtin_amdgcn_mfma_f32_16x16x32_bf16(
                    a[mi], bi[ni], accI[mi][ni], 0, 0, 0);
            }
        __builtin_amdgcn_s_setprio(0);
        __builtin_amdgcn_sched_barrier(0);

        if (t + 2 < NSTEP) {
            asm volatile("s_waitcnt vmcnt(3)" ::: "memory");   // tile t+1 landed
        } else if (t + 1 < NSTEP) {
            asm volatile("s_waitcnt vmcnt(0)" ::: "memory");
        }
        __builtin_amdgcn_s_barrier();
        __builtin_amdgcn_sched_barrier(0);

        uint32_t ta = a0; a0 = a1; a1 = a2; a2 = ta;
        uint32_t tb = b0; b0 = b1; b1 = b2; b2 = tb;
    }

    // ---- epilogue: power (bf16) [128][128] at smem+24576, col-swizzled
    uint16_t* pw16 = (uint16_t*)(smem + 24576);
    #pragma unroll
    for (int mi = 0; mi < 4; ++mi)
        #pragma unroll
        for (int ni = 0; ni < 2; ++ni)
            #pragma unroll
            for (int e = 0; e < 4; ++e) {
                int row = wm * 64 + mi * 16 + lg * 4 + e;
                int col = wn * 32 + ni * 16 + l15;
                float r = accR[mi][ni][e], im = accI[mi][ni][e];
                pw16[row * BN + (col ^ ((row & 31) << 1))] = f2bf(r * r + im * im);
            }
    __syncthreads();

    // ---- sparse mel projection + transposed store/atomic out[b][m][t]
    const int nbase = nb * BN;
    for (int idx = tid; idx < NMELS * BM; idx += 512) {
        int m  = idx >> 7;
        int ti = idx & 127;
        int lo = klo[m], w = kw[m];
        int i0 = lo < nbase ? nbase : lo;
        int i1 = (lo + w < nbase + BN) ? (lo + w) : (nbase + BN);
        if (i1 <= i0) continue;
        int g = gBase + ti;
        int b = g / NFRAMES, t = g - b * NFRAMES;
        int sw = (ti & 31) << 1;
        const uint16_t* prow = pw16 + ti * BN;
        float acc = 0.f;
        for (int j = i0; j < i1; ++j)
            acc += fbv[m * FBW + (j - lo)] * bf2f(prow[(j - nbase) ^ sw]);
        float* dst = out + (size_t)b * (NMELS * NFRAMES) + m * NFRAMES + t;
        bool full = (lo >= nbase) && (lo + w <= nbase + BN);
        if (full) *dst = acc;
        else      atomicAdd(dst, acc);
    }
}

extern "C" void kernel_launch(void* const* d_in, const int* in_sizes, int n_in,
                              void* d_out, int out_size, void* d_ws, size_t ws_size,
                              hipStream_t stream) {
    const float* wav  = (const float*)d_in[0];
    const float* win  = (const float*)d_in[1];
    const float* dre  = (const float*)d_in[2];
    const float* dimg = (const float*)d_in[3];
    const float* mfb  = (const float*)d_in[4];
    float* out = (float*)d_out;

    uint8_t* ws = (uint8_t*)d_ws;
    uint16_t* BT  = (uint16_t*)ws;                       // 1 MB
    uint16_t* wp  = (uint16_t*)(ws + (1u << 20));        // 16.9 MB
    size_t off = (1u << 20) + (size_t)NBATCH * XLEN * 2;
    int*   klo = (int*)(ws + off);
    int*   kw  = (int*)(ws + off + 640);
    float* fbv = (float*)(ws + off + 1280);

    hipLaunchKernelGGL(k_bt,   dim3(256),          dim3(256), 0, stream, dre, dimg, win, BT);
    hipLaunchKernelGGL(k_pad,  dim3(XLEN/8/256 + 1, 256), dim3(256), 0, stream, wav, wp);
    hipLaunchKernelGGL(k_fb,   dim3(1),            dim3(192), 0, stream, mfb, klo, kw, fbv);
    hipLaunchKernelGGL(k_zero, dim3(256),          dim3(256), 0, stream, klo, kw, out);
    hipLaunchKernelGGL(k_main, dim3(TOTFR / BM, 2), dim3(512), 0, stream,
                       wp, BT, klo, kw, fbv, out);
}